// Round 1
// baseline (564.492 us; speedup 1.0000x reference)
//
#include <hip/hip_runtime.h>

#define LOG2E 1.4426950408889634f
#define LN2   0.6931471805599453f

constexpr int Hh = 32;
constexpr int Pp = 3;
constexpr int Bb = 4096;
constexpr int Tt = 2048;
constexpr int Kk = 128;

constexpr int GROUP   = 16;              // lanes per batch row
constexpr int BPB     = 16;              // batch rows per block
constexpr int THREADS = BPB * GROUP;     // 256
constexpr int CH      = 64;              // timesteps per LDS chunk
constexpr int XPITCH  = 200;             // padded floats per batch row in LDS (192 used)

// ---- 16-lane rotational butterfly reduce via DPP (pure VALU) ----
template<int CTRL>
__device__ __forceinline__ float rot_add16(float v) {
    int r = __builtin_amdgcn_update_dpp(0, __float_as_int(v), CTRL, 0xF, 0xF, false);
    return v + __int_as_float(r);
}
__device__ __forceinline__ float row_sum16(float v) {
    v = rot_add16<0x121>(v);  // row_ror:1
    v = rot_add16<0x122>(v);  // row_ror:2
    v = rot_add16<0x124>(v);  // row_ror:4
    v = rot_add16<0x128>(v);  // row_ror:8
    return v;                 // every lane holds the 16-lane sum
}

// 1 / (1 + 2^g)   (sigmoid/tanh core; scale folded into gate pre-activations)
__device__ __forceinline__ float rcp1p(float g) {
    return __builtin_amdgcn_rcpf(1.0f + __builtin_amdgcn_exp2f(g));
}

__global__ void __launch_bounds__(THREADS) lstm_scan_kernel(
    const float* __restrict__ X,
    const float* __restrict__ W_ih,
    const float* __restrict__ W_hh,
    const float* __restrict__ b_ih,
    const float* __restrict__ b_hh,
    const float* __restrict__ W_hr,
    float* __restrict__ h_out)
{
    __shared__ float xs[BPB * XPITCH];

    const int tid = threadIdx.x;
    const int bl  = tid >> 4;       // batch row within block (0..15)
    const int q   = tid & 15;       // lane within group
    const int bglob = blockIdx.x * BPB;

    // lane q owns hidden units j0=q, j1=q+16 -> gate rows (i,f,g,o) for each
    const int j0 = q, j1 = q + 16;
    const int rows[8] = { j0, 32+j0, 64+j0, 96+j0, j1, 32+j1, 64+j1, 96+j1 };
    float wih[8][3], whh[8][3], bias[8];
    #pragma unroll
    for (int r = 0; r < 8; ++r) {
        const int row = rows[r];
        // sigmoid rows: scale -log2e ; tanh(g) rows: scale -2*log2e
        const float sc = ((r & 3) == 2) ? (-2.0f * LOG2E) : (-LOG2E);
        wih[r][0] = W_ih[row*3+0] * sc;
        wih[r][1] = W_ih[row*3+1] * sc;
        wih[r][2] = W_ih[row*3+2] * sc;
        whh[r][0] = W_hh[row*3+0] * sc;
        whh[r][1] = W_hh[row*3+1] * sc;
        whh[r][2] = W_hh[row*3+2] * sc;
        bias[r]   = (b_ih[row] + b_hh[row]) * sc;
    }
    const float whr0a = W_hr[0*Hh + j0], whr0b = W_hr[0*Hh + j1];
    const float whr1a = W_hr[1*Hh + j0], whr1b = W_hr[1*Hh + j1];
    const float whr2a = W_hr[2*Hh + j0], whr2b = W_hr[2*Hh + j1];

    float h0 = 0.f, h1 = 0.f, h2 = 0.f;   // projected hidden (real scale)
    float c0 = 0.f, c1 = 0.f;             // cell state for j0, j1

    for (int t0 = 0; t0 < Tt; t0 += CH) {
        __syncthreads();
        // stage X[b, t0:t0+CH, :] for the block's 16 rows: 768 float4 loads
        #pragma unroll
        for (int i = 0; i < (BPB * CH * Pp / 4) / THREADS; ++i) {  // 3 iters
            const int idx  = tid + i * THREADS;
            const int bl2  = idx / (CH * Pp / 4);   // /48
            const int off4 = idx % (CH * Pp / 4);
            const float4 v = *(const float4*)(
                X + ((size_t)(bglob + bl2) * Tt + t0) * Pp + (size_t)off4 * 4);
            *(float4*)(xs + bl2 * XPITCH + off4 * 4) = v;
        }
        __syncthreads();

        #pragma unroll 2
        for (int tt = 0; tt < CH; ++tt) {
            const float x0 = xs[bl * XPITCH + tt*3 + 0];
            const float x1 = xs[bl * XPITCH + tt*3 + 1];
            const float x2 = xs[bl * XPITCH + tt*3 + 2];

            float g[8];
            #pragma unroll
            for (int r = 0; r < 8; ++r) {
                float a = bias[r];
                a = fmaf(x0, wih[r][0], a);
                a = fmaf(x1, wih[r][1], a);
                a = fmaf(x2, wih[r][2], a);
                a = fmaf(h0, whh[r][0], a);
                a = fmaf(h1, whh[r][1], a);
                a = fmaf(h2, whh[r][2], a);
                g[r] = a;
            }
            const float si0 = rcp1p(g[0]);
            const float sf0 = rcp1p(g[1]);
            const float tg0 = fmaf(2.f, rcp1p(g[2]), -1.f);
            const float so0 = rcp1p(g[3]);
            const float si1 = rcp1p(g[4]);
            const float sf1 = rcp1p(g[5]);
            const float tg1 = fmaf(2.f, rcp1p(g[6]), -1.f);
            const float so1 = rcp1p(g[7]);

            c0 = fmaf(sf0, c0, si0 * tg0);
            c1 = fmaf(sf1, c1, si1 * tg1);

            const float tc0 = fmaf(2.f, rcp1p(c0 * (-2.f * LOG2E)), -1.f);
            const float tc1 = fmaf(2.f, rcp1p(c1 * (-2.f * LOG2E)), -1.f);
            const float a0 = so0 * tc0;
            const float a1 = so1 * tc1;

            float p0 = fmaf(a1, whr0b, a0 * whr0a);
            float p1 = fmaf(a1, whr1b, a0 * whr1a);
            float p2 = fmaf(a1, whr2b, a0 * whr2a);
            h0 = row_sum16(p0);
            h1 = row_sum16(p1);
            h2 = row_sum16(p2);
        }
    }

    if (q == 0) {
        const int b = bglob + bl;
        h_out[b*3+0] = h0;
        h_out[b*3+1] = h1;
        h_out[b*3+2] = h2;
    }
}

__global__ void __launch_bounds__(256) score_loss_kernel(
    const float* __restrict__ x5,
    const float* __restrict__ h_ws,
    float* __restrict__ partial)
{
    const int gid = blockIdx.x * 256 + threadIdx.x;
    const int b = gid >> 7;
    const int k = gid & 127;
    const float h0 = h_ws[b*3+0];
    const float h1 = h_ws[b*3+1];
    const float h2 = h_ws[b*3+2];
    const float* xb = x5 + (size_t)b * (Pp * Kk);
    const float s = fmaf(h2, xb[2*Kk + k], fmaf(h1, xb[Kk + k], h0 * xb[k]));

    // -log_sigmoid(s) = softplus(-s), stable form
    const float z  = -s;
    const float az = fabsf(z);
    const float e  = __builtin_amdgcn_exp2f(-az * LOG2E);
    float l = fmaxf(z, 0.f) + __builtin_amdgcn_logf(1.f + e) * LN2;

    #pragma unroll
    for (int m = 1; m < 64; m <<= 1) l += __shfl_xor(l, m, 64);
    __shared__ float wsum[4];
    if ((threadIdx.x & 63) == 0) wsum[threadIdx.x >> 6] = l;
    __syncthreads();
    if (threadIdx.x == 0)
        partial[blockIdx.x] = wsum[0] + wsum[1] + wsum[2] + wsum[3];
}

__global__ void __launch_bounds__(256) final_reduce_kernel(
    const float* __restrict__ partial, float* __restrict__ out)
{
    float s = 0.f;
    for (int i = threadIdx.x; i < (Bb * Kk) / 256; i += 256) s += partial[i];
    #pragma unroll
    for (int m = 1; m < 64; m <<= 1) s += __shfl_xor(s, m, 64);
    __shared__ float wsum[4];
    if ((threadIdx.x & 63) == 0) wsum[threadIdx.x >> 6] = s;
    __syncthreads();
    if (threadIdx.x == 0)
        out[0] = (wsum[0] + wsum[1] + wsum[2] + wsum[3]) * (1.0f / (float)(Bb * Kk));
}

extern "C" void kernel_launch(void* const* d_in, const int* in_sizes, int n_in,
                              void* d_out, int out_size, void* d_ws, size_t ws_size,
                              hipStream_t stream)
{
    const float* X    = (const float*)d_in[0];
    const float* x5   = (const float*)d_in[1];
    const float* W_ih = (const float*)d_in[2];
    const float* W_hh = (const float*)d_in[3];
    const float* b_ih = (const float*)d_in[4];
    const float* b_hh = (const float*)d_in[5];
    const float* W_hr = (const float*)d_in[6];
    float* out = (float*)d_out;

    float* h_ws    = (float*)d_ws;            // 4096*3 floats
    float* partial = (float*)d_ws + Bb * Pp;  // 2048 floats

    hipLaunchKernelGGL(lstm_scan_kernel, dim3(Bb / BPB), dim3(THREADS), 0, stream,
                       X, W_ih, W_hh, b_ih, b_hh, W_hr, h_ws);
    hipLaunchKernelGGL(score_loss_kernel, dim3((Bb * Kk) / 256), dim3(256), 0, stream,
                       x5, h_ws, partial);
    hipLaunchKernelGGL(final_reduce_kernel, dim3(1), dim3(256), 0, stream,
                       partial, out);
}

// Round 2
// 437.710 us; speedup vs baseline: 1.2896x; 1.2896x over previous
//
#include <hip/hip_runtime.h>

#define LOG2E 1.4426950408889634f
#define LN2   0.6931471805599453f

constexpr int Hh = 32;
constexpr int Pp = 3;
constexpr int Bb = 4096;
constexpr int Tt = 2048;
constexpr int Kk = 128;

constexpr int BPB     = 16;              // batch rows per block (16 lanes each)
constexpr int THREADS = 256;
constexpr int CH      = 64;              // timesteps per LDS chunk
constexpr int XP      = CH * 4 + 4;      // LDS floats per row: 4 per timestep + pad

typedef float v2 __attribute__((ext_vector_type(2)));

__device__ __forceinline__ v2 bc2(float x) { v2 r; r.x = x; r.y = x; return r; }

// ---- 16-lane rotational butterfly reduce via DPP (foldable: bound_ctrl=true) ----
template<int CTRL>
__device__ __forceinline__ float rot_add16(float v) {
    int r = __builtin_amdgcn_update_dpp(0, __float_as_int(v), CTRL, 0xF, 0xF, true);
    return v + __int_as_float(r);
}
__device__ __forceinline__ float row_sum16(float v) {
    v = rot_add16<0x121>(v);  // row_ror:1
    v = rot_add16<0x122>(v);  // row_ror:2
    v = rot_add16<0x124>(v);  // row_ror:4
    v = rot_add16<0x128>(v);  // row_ror:8
    return v;                 // every lane holds the 16-lane sum
}

__device__ __forceinline__ v2 rcp2(v2 d) {
    v2 r;
    r.x = __builtin_amdgcn_rcpf(d.x);
    r.y = __builtin_amdgcn_rcpf(d.y);
    return r;
}
__device__ __forceinline__ v2 exp2v(v2 g) {
    v2 r;
    r.x = __builtin_amdgcn_exp2f(g.x);
    r.y = __builtin_amdgcn_exp2f(g.y);
    return r;
}
// 1/(1+2^g) per half (sigmoid core; scale pre-folded into g)
__device__ __forceinline__ v2 rcp1p2(v2 g) {
    return rcp2(exp2v(g) + bc2(1.0f));
}

__global__ void __launch_bounds__(THREADS) lstm_scan_kernel(
    const float* __restrict__ X,
    const float* __restrict__ W_ih,
    const float* __restrict__ W_hh,
    const float* __restrict__ b_ih,
    const float* __restrict__ b_hh,
    const float* __restrict__ W_hr,
    float* __restrict__ h_out)
{
    __shared__ float xs[BPB * XP];

    const int tid = threadIdx.x;
    const int bl  = tid >> 4;       // batch row within block (0..15)
    const int q   = tid & 15;       // lane within group
    const int bglob = blockIdx.x * BPB;

    // lane q owns hidden units j0=q and j1=q+16, packed as v2 {j0, j1}.
    // gate type r: 0=i, 1=f, 2=g(tanh), 3=o
    const int j0 = q, j1 = q + 16;
    const float S1 = -LOG2E;          // sigmoid rows scale
    const float S2 = -2.0f * LOG2E;   // tanh rows scale
    v2 wih[4][3], whh[4][3], bias[4];
    #pragma unroll
    for (int r = 0; r < 4; ++r) {
        const float sc = (r == 2) ? S2 : S1;
        const int ra = r * Hh + j0, rb = r * Hh + j1;
        #pragma unroll
        for (int p = 0; p < 3; ++p) {
            wih[r][p].x = W_ih[ra*3+p] * sc;  wih[r][p].y = W_ih[rb*3+p] * sc;
            whh[r][p].x = W_hh[ra*3+p] * sc;  whh[r][p].y = W_hh[rb*3+p] * sc;
        }
        bias[r].x = (b_ih[ra] + b_hh[ra]) * sc;
        bias[r].y = (b_ih[rb] + b_hh[rb]) * sc;
    }
    v2 whr0, whr1, whr2;
    whr0.x = W_hr[0*Hh + j0]; whr0.y = W_hr[0*Hh + j1];
    whr1.x = W_hr[1*Hh + j0]; whr1.y = W_hr[1*Hh + j1];
    whr2.x = W_hr[2*Hh + j0]; whr2.y = W_hr[2*Hh + j1];

    const v2 two_s2  = bc2(2.0f * S2);   // for tgs = S2*tanh(g) = 2*S2*rcp - S2
    const v2 neg_s2  = bc2(-S2);
    const v2 two     = bc2(2.0f);
    const v2 neg_one = bc2(-1.0f);

    float h0 = 0.f, h1 = 0.f, h2 = 0.f;  // projected hidden (real scale)
    v2 c = bc2(0.f);                     // cell state, kept PRE-SCALED by S2

    for (int t0 = 0; t0 < Tt; t0 += CH) {
        __syncthreads();
        // stage X[b, t0:t0+CH, :3] into 4-float-per-timestep LDS slots
        #pragma unroll
        for (int i = 0; i < (BPB * CH * Pp) / THREADS; ++i) {  // 12 iters
            const int idx = tid + i * THREADS;
            const int row = idx / (CH * Pp);     // /192
            const int w   = idx % (CH * Pp);
            const int t   = w / 3, p = w % 3;
            xs[row * XP + t * 4 + p] =
                X[((size_t)(bglob + row) * Tt + t0 + t) * Pp + p];
        }
        __syncthreads();

        #pragma unroll 4
        for (int tt = 0; tt < CH; ++tt) {
            const float4 xv = *(const float4*)(xs + bl * XP + tt * 4);
            const v2 x0 = bc2(xv.x), x1 = bc2(xv.y), x2 = bc2(xv.z);
            const v2 hh0 = bc2(h0), hh1 = bc2(h1), hh2 = bc2(h2);

            v2 g[4];
            #pragma unroll
            for (int r = 0; r < 4; ++r) {
                v2 a = bias[r];
                a = __builtin_elementwise_fma(x0,  wih[r][0], a);
                a = __builtin_elementwise_fma(x1,  wih[r][1], a);
                a = __builtin_elementwise_fma(x2,  wih[r][2], a);
                a = __builtin_elementwise_fma(hh0, whh[r][0], a);
                a = __builtin_elementwise_fma(hh1, whh[r][1], a);
                a = __builtin_elementwise_fma(hh2, whh[r][2], a);
                g[r] = a;
            }
            const v2 si = rcp1p2(g[0]);
            const v2 sf = rcp1p2(g[1]);
            const v2 rg = rcp1p2(g[2]);
            const v2 so = rcp1p2(g[3]);
            // tgs = S2 * tanh(g) = 2*S2*rg - S2
            const v2 tgs = __builtin_elementwise_fma(two_s2, rg, neg_s2);
            // c (pre-scaled): c = sf*c + si*tgs
            c = __builtin_elementwise_fma(sf, c, si * tgs);
            // tanh(c_real) = 2*rcp(1+2^c) - 1   (c already = S2*c_real)
            const v2 tc = __builtin_elementwise_fma(two, rcp1p2(c), neg_one);
            const v2 a2 = so * tc;

            const v2 p0v = a2 * whr0;
            const v2 p1v = a2 * whr1;
            const v2 p2v = a2 * whr2;
            h0 = row_sum16(p0v.x + p0v.y);
            h1 = row_sum16(p1v.x + p1v.y);
            h2 = row_sum16(p2v.x + p2v.y);
        }
    }

    if (q == 0) {
        const int b = bglob + bl;
        h_out[b*3+0] = h0;
        h_out[b*3+1] = h1;
        h_out[b*3+2] = h2;
    }
}

__global__ void __launch_bounds__(256) score_loss_kernel(
    const float* __restrict__ x5,
    const float* __restrict__ h_ws,
    float* __restrict__ partial)
{
    const int gid = blockIdx.x * 256 + threadIdx.x;
    const int b = gid >> 7;
    const int k = gid & 127;
    const float h0 = h_ws[b*3+0];
    const float h1 = h_ws[b*3+1];
    const float h2 = h_ws[b*3+2];
    const float* xb = x5 + (size_t)b * (Pp * Kk);
    const float s = fmaf(h2, xb[2*Kk + k], fmaf(h1, xb[Kk + k], h0 * xb[k]));

    // -log_sigmoid(s) = softplus(-s), stable form
    const float z  = -s;
    const float az = fabsf(z);
    const float e  = __builtin_amdgcn_exp2f(-az * LOG2E);
    float l = fmaxf(z, 0.f) + __builtin_amdgcn_logf(1.f + e) * LN2;

    #pragma unroll
    for (int m = 1; m < 64; m <<= 1) l += __shfl_xor(l, m, 64);
    __shared__ float wsum[4];
    if ((threadIdx.x & 63) == 0) wsum[threadIdx.x >> 6] = l;
    __syncthreads();
    if (threadIdx.x == 0)
        partial[blockIdx.x] = wsum[0] + wsum[1] + wsum[2] + wsum[3];
}

__global__ void __launch_bounds__(256) final_reduce_kernel(
    const float* __restrict__ partial, float* __restrict__ out)
{
    float s = 0.f;
    for (int i = threadIdx.x; i < (Bb * Kk) / 256; i += 256) s += partial[i];
    #pragma unroll
    for (int m = 1; m < 64; m <<= 1) s += __shfl_xor(s, m, 64);
    __shared__ float wsum[4];
    if ((threadIdx.x & 63) == 0) wsum[threadIdx.x >> 6] = s;
    __syncthreads();
    if (threadIdx.x == 0)
        out[0] = (wsum[0] + wsum[1] + wsum[2] + wsum[3]) * (1.0f / (float)(Bb * Kk));
}

extern "C" void kernel_launch(void* const* d_in, const int* in_sizes, int n_in,
                              void* d_out, int out_size, void* d_ws, size_t ws_size,
                              hipStream_t stream)
{
    const float* X    = (const float*)d_in[0];
    const float* x5   = (const float*)d_in[1];
    const float* W_ih = (const float*)d_in[2];
    const float* W_hh = (const float*)d_in[3];
    const float* b_ih = (const float*)d_in[4];
    const float* b_hh = (const float*)d_in[5];
    const float* W_hr = (const float*)d_in[6];
    float* out = (float*)d_out;

    float* h_ws    = (float*)d_ws;            // 4096*3 floats
    float* partial = (float*)d_ws + Bb * Pp;  // 2048 floats

    hipLaunchKernelGGL(lstm_scan_kernel, dim3(Bb / BPB), dim3(THREADS), 0, stream,
                       X, W_ih, W_hh, b_ih, b_hh, W_hr, h_ws);
    hipLaunchKernelGGL(score_loss_kernel, dim3((Bb * Kk) / 256), dim3(256), 0, stream,
                       x5, h_ws, partial);
    hipLaunchKernelGGL(final_reduce_kernel, dim3(1), dim3(256), 0, stream,
                       partial, out);
}